// Round 1
// baseline (88.074 us; speedup 1.0000x reference)
//
#include <hip/hip_runtime.h>

// HilbertSimulator — closed-form reduction.
//
// Reference circuit: RY(x_i) then RY(w_i) per qubit on |0000> (RY compose:
// angle theta_i = x_i + w_i -> product state), then 4 CNOTs (a GF(2)-linear
// permutation), then probs @ Z. Z-expectation of an XOR-of-bits factorizes
// over a product distribution into a product of cos(2*theta_i):
//   d_i = cos(2*(x_i + w_i))
//   out = ( d1*d2*d3, d0*d1, d0*d1*d2, d0*d1*d2*d3 )
//
// v2: pure-streaming tuning. 4 elements/thread via grid-stride (4 independent
// dwordx4 loads in flight per lane -> 4x memory-level parallelism) and
// nontemporal load/store hints (single-use streams, skip L2 allocation).
// Traffic is fixed at 67.1 MB; target is the ~10.7 us HBM roofline.

typedef float f32x4 __attribute__((ext_vector_type(4)));

__device__ __forceinline__ f32x4 hilbert_out(const f32x4 xv,
                                             const float w0, const float w1,
                                             const float w2, const float w3) {
    const float d0 = __cosf(2.0f * (xv[0] + w0));
    const float d1 = __cosf(2.0f * (xv[1] + w1));
    const float d2 = __cosf(2.0f * (xv[2] + w2));
    const float d3 = __cosf(2.0f * (xv[3] + w3));
    f32x4 o;
    o[1] = d0 * d1;          // <Z1> = d0*d1
    o[0] = d1 * d2 * d3;     // <Z0> = d1*d2*d3
    o[2] = o[1] * d2;        // <Z2> = d0*d1*d2
    o[3] = o[2] * d3;        // <Z3> = d0*d1*d2*d3
    return o;
}

__global__ __launch_bounds__(256) void HilbertSimulator_12275016532163_kernel(
    const f32x4* __restrict__ x,   // (BATCH, 4) as 16B vectors
    const float* __restrict__ w,   // (1, 4) -> scalar loads (uniform)
    f32x4*       __restrict__ out, // (BATCH, 4) as 16B vectors
    int batch)
{
    const float w0 = w[0], w1 = w[1], w2 = w[2], w3 = w[3];

    const int stride = gridDim.x * blockDim.x;
    int b = blockIdx.x * blockDim.x + threadIdx.x;

    // Main body: 4 independent coalesced 16B loads in flight per lane.
    // With grid sized at batch/(256*4), this runs exactly once per thread.
    for (; b + 3 * stride < batch; b += 4 * stride) {
        const f32x4 v0 = __builtin_nontemporal_load(&x[b]);
        const f32x4 v1 = __builtin_nontemporal_load(&x[b + stride]);
        const f32x4 v2 = __builtin_nontemporal_load(&x[b + 2 * stride]);
        const f32x4 v3 = __builtin_nontemporal_load(&x[b + 3 * stride]);

        __builtin_nontemporal_store(hilbert_out(v0, w0, w1, w2, w3), &out[b]);
        __builtin_nontemporal_store(hilbert_out(v1, w0, w1, w2, w3), &out[b + stride]);
        __builtin_nontemporal_store(hilbert_out(v2, w0, w1, w2, w3), &out[b + 2 * stride]);
        __builtin_nontemporal_store(hilbert_out(v3, w0, w1, w2, w3), &out[b + 3 * stride]);
    }
    // Tail (not taken for BATCH = 2^21 with the launch config below).
    for (; b < batch; b += stride) {
        const f32x4 v = __builtin_nontemporal_load(&x[b]);
        __builtin_nontemporal_store(hilbert_out(v, w0, w1, w2, w3), &out[b]);
    }
}

extern "C" void kernel_launch(void* const* d_in, const int* in_sizes, int n_in,
                              void* d_out, int out_size, void* d_ws, size_t ws_size,
                              hipStream_t stream) {
    const f32x4* x = (const f32x4*)d_in[0];
    const float* w = (const float*)d_in[1];
    f32x4* out = (f32x4*)d_out;

    const int batch = in_sizes[0] / 4;   // x is (BATCH, 4) fp32
    const int block = 256;
    const int ept   = 4;                 // elements per thread
    int threads = (batch + ept - 1) / ept;
    int grid = (threads + block - 1) / block;
    if (grid < 1) grid = 1;
    // BATCH = 2097152 -> grid = 2048, stride = 524288, exactly 4 elems/thread.

    HilbertSimulator_12275016532163_kernel<<<grid, block, 0, stream>>>(x, w, out, batch);
}

// Round 2
// 81.554 us; speedup vs baseline: 1.0800x; 1.0800x over previous
//
#include <hip/hip_runtime.h>

// HilbertSimulator — closed-form reduction.
//
// Reference circuit: RY(x_i) then RY(w_i) per qubit on |0000> (RY compose:
// angle theta_i = x_i + w_i -> product state), then 4 CNOTs (a GF(2)-linear
// permutation), then probs @ Z. Z-expectation of an XOR-of-bits factorizes
// over a product distribution into a product of cos(2*theta_i):
//   d_i = cos(2*(x_i + w_i))
//   out = ( d1*d2*d3, d0*d1, d0*d1*d2, d0*d1*d2*d3 )
//
// v3: back to v1's plain-load/plain-store skeleton (v2's nontemporal +
// 8MB-strided loads regressed or was noise; the harness fill kernels prove
// plain stores reach 6.33 TB/s). Single change vs v1: 2 elements/thread,
// block-contiguous (two fully-coalesced dwordx4 loads 4KB apart, issued
// back-to-back -> 2x memory-level parallelism per lane, same DRAM-row
// neighborhood). Traffic fixed at 67.1 MB; kernel roofline ~10.7 us.

typedef float f32x4 __attribute__((ext_vector_type(4)));

__device__ __forceinline__ f32x4 hilbert_out(const f32x4 xv,
                                             const float w0, const float w1,
                                             const float w2, const float w3) {
    const float d0 = __cosf(2.0f * (xv[0] + w0));
    const float d1 = __cosf(2.0f * (xv[1] + w1));
    const float d2 = __cosf(2.0f * (xv[2] + w2));
    const float d3 = __cosf(2.0f * (xv[3] + w3));
    f32x4 o;
    o[1] = d0 * d1;          // <Z1> = d0*d1
    o[0] = d1 * d2 * d3;     // <Z0> = d1*d2*d3
    o[2] = o[1] * d2;        // <Z2> = d0*d1*d2
    o[3] = o[2] * d3;        // <Z3> = d0*d1*d2*d3
    return o;
}

__global__ __launch_bounds__(256) void HilbertSimulator_12275016532163_kernel(
    const f32x4* __restrict__ x,   // (BATCH, 4) as 16B vectors
    const float* __restrict__ w,   // (1, 4) -> scalar loads (uniform)
    f32x4*       __restrict__ out, // (BATCH, 4) as 16B vectors
    int batch)
{
    const float w0 = w[0], w1 = w[1], w2 = w[2], w3 = w[3];

    // Block covers 2*blockDim contiguous elements; each thread owns two,
    // one in each half. Both loads are fully coalesced (16B/lane,
    // consecutive lanes -> consecutive addresses) and independent.
    const int b0 = blockIdx.x * (blockDim.x * 2) + threadIdx.x;
    const int b1 = b0 + blockDim.x;

    if (b1 < batch) {
        const f32x4 v0 = x[b0];          // both loads issue before either
        const f32x4 v1 = x[b1];          // result is consumed (MLP = 2)
        out[b0] = hilbert_out(v0, w0, w1, w2, w3);
        out[b1] = hilbert_out(v1, w0, w1, w2, w3);
    } else if (b0 < batch) {
        out[b0] = hilbert_out(x[b0], w0, w1, w2, w3);
    }
}

extern "C" void kernel_launch(void* const* d_in, const int* in_sizes, int n_in,
                              void* d_out, int out_size, void* d_ws, size_t ws_size,
                              hipStream_t stream) {
    const f32x4* x = (const f32x4*)d_in[0];
    const float* w = (const float*)d_in[1];
    f32x4* out = (f32x4*)d_out;

    const int batch = in_sizes[0] / 4;   // x is (BATCH, 4) fp32
    const int block = 256;
    const int ept   = 2;                 // elements per thread
    int grid = (batch + block * ept - 1) / (block * ept);
    if (grid < 1) grid = 1;
    // BATCH = 2097152 -> grid = 4096, exactly 2 elems/thread, no tail.

    HilbertSimulator_12275016532163_kernel<<<grid, block, 0, stream>>>(x, w, out, batch);
}